// Round 13
// baseline (2630.988 us; speedup 1.0000x reference)
//
#include <hip/hip_runtime.h>

// 16-qubit statevector, 512 samples, 6 StronglyEntanglingLayers, qubit q <-> bit q.
// Round 20: r19's alternating layouts made RACE-FREE via double buffering.
// r12 failed because in-place relayout (read pi_B, write pi_A, same buffer) lets
// block X's layout-A writes clobber layout-B inputs other blocks haven't read.
// Now: P reads layout B from st1, writes layout A to st0; Q reads A from st0,
// writes B to st1; finalK reads B from st1. Reads/writes never share a buffer.
// Every sweep WRITES at 512B per-thread loop stride (clean profile: r11-P) and
// reads at 16KB stride (L3-resident chunk). Evidence for the stride rule:
// r9-Q/r11-Q byte-identical 1.75x FETCH+WRITE amplification at 16KB store
// loops across two different coverage layouts; all <=512B-loop kernels clean.
// Gate logic byte-identical to r11 (passed correctness).
//
// Tilings (r = l+1):
//   P(l) [32 amps]: E=a0-4 | tid3-5=a5-7 | tid0-2=a13-15 | waves=a8-10 | fb=a11-12.
//        wraps_{l-1}, R_l(0-4) local, R_l(5-7) masks 8,16,32, prefix (t=r..7).
//   Q(l) [32 amps]: E=a8-12 | tid0-2=a5-7 | tid3-5=a13-15 | waves=a0-2 | fb=a3-4.
//        R_l(8-12) local, R_l(13-15) masks 8,16,32, mid (t=8..15).
//   P(0): init (all 16 layer-0 rots folded) + prefix; writes A to st0.
//   finalK: wraps_5 + measurement, P-tiling, reads B from st1.
// Layout A: p0-2=a5-7 | p3-5=a13-15 | p6-10=a0-4  | p11-13=a8-10 | p14-15=a11-12
// Layout B: p0-2=a5-7 | p3-5=a13-15 | p6-10=a8-12 | p11-13=a0-2  | p14-15=a3-4
// Chunk = 128 samples (2 x 64 MB buffers, L3-resident).

#define NTH 512
typedef float v32f __attribute__((ext_vector_type(32)));

template <int I> struct IC { static constexpr int value = I; };
template <int N, int I = 0, typename F>
__device__ __forceinline__ void static_for(F&& f) {
  if constexpr (I < N) { f(IC<I>{}); static_for<N, I + 1>(f); }
}

// ---------------- gate helpers on 32 reg amps ----------------

template <int LB>  // Rot on local e-bit LB
__device__ __forceinline__ void rot_local(v32f& ar, v32f& ai, const float* __restrict__ u) {
  const float u00r = u[0], u00i = u[1], u01r = u[2], u01i = u[3];
  const float u10r = u[4], u10i = u[5], u11r = u[6], u11i = u[7];
  static_for<16>([&](auto hc) {
    constexpr int h = hc.value;
    constexpr int e0 = ((h >> LB) << (LB + 1)) | (h & ((1 << LB) - 1));
    constexpr int e1 = e0 | (1 << LB);
    const float axr = ar[e0], axi = ai[e0], bxr = ar[e1], bxi = ai[e1];
    ar[e0] = u00r * axr - u00i * axi + u01r * bxr - u01i * bxi;
    ai[e0] = u00r * axi + u00i * axr + u01r * bxi + u01i * bxr;
    ar[e1] = u10r * axr - u10i * axi + u11r * bxr - u11i * bxi;
    ai[e1] = u10r * axi + u10i * axr + u11r * bxi + u11i * bxr;
  });
}

// Rot on a lane bit -- ONLY ever called with masks 8,16,32 (tid3-5).
__device__ __forceinline__ void rot_lane(v32f& ar, v32f& ai, const float* __restrict__ u,
                                         const int m, const int bit) {
  const float car = bit ? u[6] : u[0], cai = bit ? u[7] : u[1];
  const float cbr = bit ? u[4] : u[2], cbi = bit ? u[5] : u[3];
  static_for<32>([&](auto ec) {
    constexpr int e = ec.value;
    const float orr = ar[e], oii = ai[e];
    const float pr = __shfl_xor(orr, m);
    const float pi = __shfl_xor(oii, m);
    ar[e] = car * orr - cai * oii + cbr * pr - cbi * pi;
    ai[e] = car * oii + cai * orr + cbr * pi + cbi * pr;
  });
}

// CNOT, local e-bit target TB; LOCALLO = qubit index of e-bit 0; control qubit C.
template <int TB, int LOCALLO, int C>
__device__ __forceinline__ void cnot_local(v32f& ar, v32f& ai, const int ibase) {
  static_for<16>([&](auto hc) {
    constexpr int h = hc.value;
    constexpr int e0 = ((h >> TB) << (TB + 1)) | (h & ((1 << TB) - 1));
    constexpr int e1 = e0 | (1 << TB);
    if constexpr (C >= LOCALLO && C < LOCALLO + 5) {
      if constexpr ((e0 >> (C - LOCALLO)) & 1) {  // static: pure register swap
        const float tr = ar[e0], ti = ai[e0];
        ar[e0] = ar[e1]; ai[e0] = ai[e1];
        ar[e1] = tr;     ai[e1] = ti;
      }
    } else {
      const int take = (ibase >> C) & 1;
      const float axr = ar[e0], axi = ai[e0], bxr = ar[e1], bxi = ai[e1];
      ar[e0] = take ? bxr : axr; ai[e0] = take ? bxi : axi;
      ar[e1] = take ? axr : bxr; ai[e1] = take ? axi : bxi;
    }
  });
}

// CNOT, lane-bit target (mask m in {8,16,32}); control qubit C (C != target).
template <int LOCALLO, int C>
__device__ __forceinline__ void cnot_lane(v32f& ar, v32f& ai, const int m, const int ibase) {
  if constexpr (C >= LOCALLO && C < LOCALLO + 5) {
    static_for<32>([&](auto ec) {
      constexpr int e = ec.value;
      if constexpr ((e >> (C - LOCALLO)) & 1) {
        ar[e] = __shfl_xor(ar[e], m);
        ai[e] = __shfl_xor(ai[e], m);
      }
    });
  } else {
    const int take = (ibase >> C) & 1;
    static_for<32>([&](auto ec) {
      constexpr int e = ec.value;
      const float pr = __shfl_xor(ar[e], m);
      const float pi = __shfl_xor(ai[e], m);
      ar[e] = take ? pr : ar[e];
      ai[e] = take ? pi : ai[e];
    });
  }
}

// ---------------- prep: 96 Rot matrices ----------------
__global__ void qsim_prep(const float* __restrict__ w, float* __restrict__ gm) {
  const int i = threadIdx.x;
  if (i < 96) {
    const float phi = w[i * 3 + 0];
    const float th  = w[i * 3 + 1];
    const float om  = w[i * 3 + 2];
    float st, ct; sincosf(0.5f * th, &st, &ct);
    float sa, ca; sincosf(0.5f * (phi + om), &sa, &ca);
    float sb, cb; sincosf(0.5f * (phi - om), &sb, &cb);
    float* u = gm + i * 8;
    u[0] =  ct * ca; u[1] = -ct * sa;   // m00
    u[2] = -st * cb; u[3] = -st * sb;   // m01
    u[4] =  st * cb; u[5] = -st * sb;   // m10
    u[6] =  ct * ca; u[7] =  ct * sa;   // m11
  }
}

// ---------------- Sweep P : rots 0-7, prefix; reads B from sin, writes A to sout ----------------
template <int L>
__global__ void __launch_bounds__(NTH) sweepP(const float2* __restrict__ sin,
                                              float2* __restrict__ sout,
                                              const float* __restrict__ x,
                                              const float* __restrict__ gm) {
  const int tid = threadIdx.x;
  const int s  = blockIdx.x >> 2;
  const int fb = blockIdx.x & 3;
  // amp: a0-4=e | a5-7=tid3-5 | a8-10=tid6-8 | a11-12=fb | a13-15=tid0-2
  const int ibase = (((tid >> 3) & 7) << 5) | (((tid >> 6) & 7) << 8) |
                    (fb << 11) | ((tid & 7) << 13);
  // READ layout B: a5-7->p0-2, a13-15->p3-5, a8-10->p6-8, a11-12->p9-10, a0-4->p11-15
  const int rpb = ((tid >> 3) & 7) | ((tid & 7) << 3) |
                  (((tid >> 6) & 7) << 6) | (fb << 9);
  // WRITE layout A: a5-7->p0-2, a13-15->p3-5, a0-4->p6-10, a8-10->p11-13, a11-12->p14-15
  const int wpb = ((tid >> 3) & 7) | ((tid & 7) << 3) |
                  (((tid >> 6) & 7) << 11) | (fb << 14);
  const float2* __restrict__ rbase = sin + (s << 16) + rpb;
  float2* __restrict__ wbase = sout + (s << 16) + wpb;
  constexpr int r = L + 1;
  const float* __restrict__ gl = gm + L * 128;
  v32f ar, ai;

  if constexpr (L == 0) {
    // init: |psi> = prod_q v_q, v_q = Rot_0(q)*RX(x_q)|0>  (ALL 16 rots folded)
    __shared__ float iv[16][4];
    if (tid < 16) {
      const float* u = gm + tid * 8;
      float sx, cx; sincosf(0.5f * x[s * 16 + tid], &sx, &cx);
      iv[tid][0] = u[0] * cx + u[3] * sx;
      iv[tid][1] = u[1] * cx - u[2] * sx;
      iv[tid][2] = u[4] * cx + u[7] * sx;
      iv[tid][3] = u[5] * cx - u[6] * sx;
    }
    __syncthreads();
    float Tr = 1.f, Ti = 0.f;
    #pragma unroll
    for (int b = 5; b <= 15; ++b) {
      const int bit = (ibase >> b) & 1;
      const float fr = iv[b][2 * bit], fi = iv[b][2 * bit + 1];
      const float nr = Tr * fr - Ti * fi; Ti = Tr * fi + Ti * fr; Tr = nr;
    }
    ar[0] = Tr; ai[0] = Ti;
    static_for<5>([&](auto bc) {
      constexpr int bI = bc.value;
      const float v0r = iv[bI][0], v0i = iv[bI][1], v1r = iv[bI][2], v1i = iv[bI][3];
      static_for<(1 << bI)>([&](auto kc) {
        constexpr int k = kc.value;
        constexpr int k1 = k | (1 << bI);
        const float kr = ar[k], ki = ai[k];
        ar[k1] = kr * v1r - ki * v1i; ai[k1] = kr * v1i + ki * v1r;
        ar[k]  = kr * v0r - ki * v0i; ai[k]  = kr * v0i + ki * v0r;
      });
    });
  } else {
    #pragma unroll
    for (int e = 0; e < 32; ++e) {         // layout-B reads (16KB loop, L3-resident)
      const float2 v = rbase[e << 11];
      ar[e] = v.x; ai[e] = v.y;
    }
    // deferred wraps of layer L-1: t=k (local), c=16-L+k in a11-15 (ibase)
    static_for<L>([&](auto kc) {
      constexpr int k = kc.value;
      constexpr int C = 16 - L + k;
      cnot_local<k, 0, C>(ar, ai, ibase);
    });
    rot_local<0>(ar, ai, gl);
    rot_local<1>(ar, ai, gl + 8);
    rot_local<2>(ar, ai, gl + 16);
    rot_local<3>(ar, ai, gl + 24);
    rot_local<4>(ar, ai, gl + 32);
    rot_lane(ar, ai, gl + 40, 8,  (tid >> 3) & 1);   // R_L(5)
    rot_lane(ar, ai, gl + 48, 16, (tid >> 4) & 1);   // R_L(6)
    rot_lane(ar, ai, gl + 56, 32, (tid >> 5) & 1);   // R_L(7)
  }

  // ring prefix: g = 0..7-r, t = g+r in [r,7]
  static_for<8 - r>([&](auto gc) {
    constexpr int g = gc.value;
    constexpr int t = g + r;
    if constexpr (t <= 4) cnot_local<t, 0, g>(ar, ai, ibase);
    else                  cnot_lane<0, g>(ar, ai, 1 << (t - 2), ibase);  // 5,6,7 -> 8,16,32
  });

  #pragma unroll
  for (int e = 0; e < 32; ++e) {           // layout-A writes, 512B loop (clean)
    float2 v; v.x = ar[e]; v.y = ai[e];
    wbase[e << 6] = v;
  }
}

// ---------------- Sweep Q : rots 8-15, ring mid; reads A from sin, writes B to sout ----------------
template <int L>
__global__ void __launch_bounds__(NTH) sweepQ(const float2* __restrict__ sin,
                                              float2* __restrict__ sout,
                                              const float* __restrict__ gm) {
  const int tid = threadIdx.x;
  const int s  = blockIdx.x >> 2;
  const int fb = blockIdx.x & 3;
  // amp: a8-12=e | a5-7=tid0-2 | a13-15=tid3-5 | a0-2=tid6-8 | a3-4=fb
  const int ibase = ((tid >> 6) & 7) | (fb << 3) | ((tid & 7) << 5) |
                    (((tid >> 3) & 7) << 13);
  // READ layout A: a5-7->p0-2, a13-15->p3-5, a0-2->p6-8, a3-4->p9-10, a8-12->p11-15
  const int rpb = (tid & 7) | (((tid >> 3) & 7) << 3) |
                  (((tid >> 6) & 7) << 6) | (fb << 9);
  // WRITE layout B: a5-7->p0-2, a13-15->p3-5, a8-12->p6-10, a0-2->p11-13, a3-4->p14-15
  const int wpb = (tid & 7) | (((tid >> 3) & 7) << 3) |
                  (((tid >> 6) & 7) << 11) | (fb << 14);
  const float2* __restrict__ rbase = sin + (s << 16) + rpb;
  float2* __restrict__ wbase = sout + (s << 16) + wpb;
  constexpr int r = L + 1;
  const float* __restrict__ gl = gm + L * 128;
  v32f ar, ai;
  #pragma unroll
  for (int e = 0; e < 32; ++e) {           // layout-A reads (16KB loop, L3-resident)
    const float2 v = rbase[e << 11];
    ar[e] = v.x; ai[e] = v.y;
  }
  if constexpr (L > 0) {  // layer 0's rots were folded into init
    rot_local<0>(ar, ai, gl + 64);                   // R_L(8)
    rot_local<1>(ar, ai, gl + 72);                   // R_L(9)
    rot_local<2>(ar, ai, gl + 80);                   // R_L(10)
    rot_local<3>(ar, ai, gl + 88);                   // R_L(11)
    rot_local<4>(ar, ai, gl + 96);                   // R_L(12)
    rot_lane(ar, ai, gl + 104, 8,  (tid >> 3) & 1);  // R_L(13)
    rot_lane(ar, ai, gl + 112, 16, (tid >> 4) & 1);  // R_L(14)
    rot_lane(ar, ai, gl + 120, 32, (tid >> 5) & 1);  // R_L(15)
  }
  // ring mid: g = 8-r..15-r, t = g+r in [8,15]
  static_for<8>([&](auto gc) {
    constexpr int g = 8 - r + gc.value;
    constexpr int t = g + r;
    if constexpr (t <= 12) cnot_local<t - 8, 8, g>(ar, ai, ibase);
    else                   cnot_lane<8, g>(ar, ai, 1 << (t - 10), ibase);  // 13,14,15 -> 8,16,32
  });

  #pragma unroll
  for (int e = 0; e < 32; ++e) {           // layout-B writes, 512B loop (clean)
    float2 v; v.x = ar[e]; v.y = ai[e];
    wbase[e << 6] = v;
  }
}

// ---------------- final: wraps_5 + measurement (reads layout B, P-tiling) ----------------
__global__ void __launch_bounds__(NTH) finalK(const float2* __restrict__ sin,
                                              float* __restrict__ part) {
  const int tid = threadIdx.x;
  const int s  = blockIdx.x >> 2;
  const int fb = blockIdx.x & 3;
  const int ibase = (((tid >> 3) & 7) << 5) | (((tid >> 6) & 7) << 8) |
                    (fb << 11) | ((tid & 7) << 13);
  const int rpb = ((tid >> 3) & 7) | ((tid & 7) << 3) |
                  (((tid >> 6) & 7) << 6) | (fb << 9);
  const float2* __restrict__ rbase = sin + (s << 16) + rpb;
  v32f ar, ai;
  #pragma unroll
  for (int e = 0; e < 32; ++e) {
    const float2 v = rbase[e << 11];
    ar[e] = v.x; ai[e] = v.y;
  }
  // wraps_5 (r=6): t=k (k=0..5), c=10+k (a10 wave, a11-12 fb, a13-15 tid0-2)
  static_for<6>([&](auto kc) {
    constexpr int k = kc.value;
    constexpr int C = 10 + k;
    if constexpr (k <= 4) cnot_local<k, 0, C>(ar, ai, ibase);
    else                  cnot_lane<0, C>(ar, ai, 8, ibase);   // t=5 -> tid3 mask 8
  });
  __shared__ float red[8][16];
  float tot = 0.f, sl0 = 0.f, sl1 = 0.f, sl2 = 0.f, sl3 = 0.f, sl4 = 0.f;
  static_for<32>([&](auto ec) {
    constexpr int e = ec.value;
    const float p = ar[e] * ar[e] + ai[e] * ai[e];
    tot += p;
    if constexpr (e & 1)  sl0 -= p; else sl0 += p;
    if constexpr (e & 2)  sl1 -= p; else sl1 += p;
    if constexpr (e & 4)  sl2 -= p; else sl2 += p;
    if constexpr (e & 8)  sl3 -= p; else sl3 += p;
    if constexpr (e & 16) sl4 -= p; else sl4 += p;
  });
  const float sl[5] = {sl0, sl1, sl2, sl3, sl4};
  const int wv = tid >> 6;
  static_for<16>([&](auto qc) {
    constexpr int q = qc.value;
    float v;
    if constexpr (q < 5) v = sl[q];
    else v = ((ibase >> q) & 1) ? -tot : tot;
    v += __shfl_xor(v, 1);  v += __shfl_xor(v, 2);  v += __shfl_xor(v, 4);
    v += __shfl_xor(v, 8);  v += __shfl_xor(v, 16); v += __shfl_xor(v, 32);
    if ((tid & 63) == 0) red[wv][q] = v;
  });
  __syncthreads();
  if (tid < 16) {
    float a = 0.f;
    #pragma unroll
    for (int w8 = 0; w8 < 8; ++w8) a += red[w8][tid];
    part[blockIdx.x * 16 + tid] = a;
  }
}

// ---------------- final reduce: 4 block-partials -> out ----------------
__global__ void __launch_bounds__(NTH) reduceK(const float* __restrict__ part,
                                               float* __restrict__ out) {
  const int j = blockIdx.x * NTH + threadIdx.x;  // j = s*16 + q, j < 8192
  const int s = j >> 4, q = j & 15;
  float a = 0.f;
  #pragma unroll
  for (int f = 0; f < 4; ++f) a += part[(s << 6) + f * 16 + q];
  out[j] = a;
}

extern "C" void kernel_launch(void* const* d_in, const int* in_sizes, int n_in,
                              void* d_out, int out_size, void* d_ws, size_t ws_size,
                              hipStream_t stream) {
  (void)in_sizes; (void)n_in; (void)out_size;
  const float* x = (const float*)d_in[0];
  const float* w = (const float*)d_in[1];
  float* out = (float*)d_out;
  float* gm   = (float*)d_ws;                          // 768 floats
  float* part = (float*)((char*)d_ws + 4096);          // 512*4*16 floats = 128 KB
  // double-buffered state: 2 x chunk x 512KB starting at offset 512KB
  const size_t avail = ws_size > 524288 ? ws_size - 524288 : 0;
  long long chunk = (long long)(avail / 1048576);      // 1 MB per sample (2 buffers)
  if (chunk > 128) chunk = 128;                        // 2 x 64 MB: L3-resident
  if (chunk < 1) chunk = 1;
  float2* st0 = (float2*)((char*)d_ws + 524288);
  float2* st1 = (float2*)((char*)d_ws + 524288 + (size_t)chunk * 524288);

  qsim_prep<<<dim3(1), dim3(128), 0, stream>>>(w, gm);
  for (int s0 = 0; s0 < 512; s0 += (int)chunk) {
    const int ns = (512 - s0) < (int)chunk ? (512 - s0) : (int)chunk;
    const dim3 g(ns * 4), b(NTH);
    const float* xs = x + s0 * 16;
    float* pp = part + (size_t)s0 * 64;
    sweepP<0><<<g, b, 0, stream>>>(st1, st0, xs, gm);   // init: writes A to st0
    sweepQ<0><<<g, b, 0, stream>>>(st0, st1, gm);       // reads A, writes B
    sweepP<1><<<g, b, 0, stream>>>(st1, st0, xs, gm);   // reads B, writes A
    sweepQ<1><<<g, b, 0, stream>>>(st0, st1, gm);
    sweepP<2><<<g, b, 0, stream>>>(st1, st0, xs, gm);
    sweepQ<2><<<g, b, 0, stream>>>(st0, st1, gm);
    sweepP<3><<<g, b, 0, stream>>>(st1, st0, xs, gm);
    sweepQ<3><<<g, b, 0, stream>>>(st0, st1, gm);
    sweepP<4><<<g, b, 0, stream>>>(st1, st0, xs, gm);
    sweepQ<4><<<g, b, 0, stream>>>(st0, st1, gm);
    sweepP<5><<<g, b, 0, stream>>>(st1, st0, xs, gm);
    sweepQ<5><<<g, b, 0, stream>>>(st0, st1, gm);
    finalK<<<g, b, 0, stream>>>(st1, pp);               // reads B
  }
  reduceK<<<dim3(16), dim3(NTH), 0, stream>>>(part, out);
}

// Round 14
// 2226.063 us; speedup vs baseline: 1.1819x; 1.1819x over previous
//
#include <hip/hip_runtime.h>

// 16-qubit statevector, 512 samples, 6 StronglyEntanglingLayers, qubit q <-> bit q.
// Round 21: r11 (=r18) + XOR address skew. r11 passed correctness; its only
// defect: Q's 16KB-stride loop keeps address bits 6-13 constant across the 32
// chunks -> L2-set/HBM-channel concentration -> contention + in-place 1.75x
// write amp (r11), and latency-bound reads even when traffic is clean (r13).
// Fix: storage bijection phys = lin ^ (((lin>>11)&31)<<6) (involution; bits
// 11-15 untouched). P's loop varies lin bits 6-10 -> skew constant within its
// contiguous 16KB (harmless). Q's loop varies bits 11-15 -> skewed bits 6-10
// = wave^e now vary per chunk -> spread across sets/channels. Wave-level 512B
// contiguity (bits 0-5) preserved in both kernels. Gate logic identical to r11.
//
// Tilings (r = l+1):
//   P(l) [32 amps]: E=a0-4 | tid3-5=a5-7 | tid0-2=a13-15 | waves=a8-10 | fb=a11-12.
//        wraps_{l-1}, R_l(0-4) local, R_l(5-7) masks 8,16,32, prefix (t=r..7).
//   Q(l) [32 amps]: E=a8-12 | tid0-2=a5-7 | tid3-5=a13-15 | waves=a0-2 | fb=a3-4.
//        R_l(8-12) local, R_l(13-15) masks 8,16,32, mid (t=8..15).
//   P(0): init (all 16 layer-0 rots folded) + prefix.
//   finalK: wraps_5 + measurement, P-tiling. ZERO rots on tid0-2 anywhere.
// Linear layout: p0-2=a5-7 | p3-5=a13-15 | p6-10=a0-4 | p11-15=a8-12; stored
// at phys = lin ^ (((lin>>11)&31)<<6). Chunk = 256 samples (128 MB), in place.

#define NTH 512
typedef float v32f __attribute__((ext_vector_type(32)));

template <int I> struct IC { static constexpr int value = I; };
template <int N, int I = 0, typename F>
__device__ __forceinline__ void static_for(F&& f) {
  if constexpr (I < N) { f(IC<I>{}); static_for<N, I + 1>(f); }
}

// ---------------- gate helpers on 32 reg amps ----------------

template <int LB>  // Rot on local e-bit LB
__device__ __forceinline__ void rot_local(v32f& ar, v32f& ai, const float* __restrict__ u) {
  const float u00r = u[0], u00i = u[1], u01r = u[2], u01i = u[3];
  const float u10r = u[4], u10i = u[5], u11r = u[6], u11i = u[7];
  static_for<16>([&](auto hc) {
    constexpr int h = hc.value;
    constexpr int e0 = ((h >> LB) << (LB + 1)) | (h & ((1 << LB) - 1));
    constexpr int e1 = e0 | (1 << LB);
    const float axr = ar[e0], axi = ai[e0], bxr = ar[e1], bxi = ai[e1];
    ar[e0] = u00r * axr - u00i * axi + u01r * bxr - u01i * bxi;
    ai[e0] = u00r * axi + u00i * axr + u01r * bxi + u01i * bxr;
    ar[e1] = u10r * axr - u10i * axi + u11r * bxr - u11i * bxi;
    ai[e1] = u10r * axi + u10i * axr + u11r * bxi + u11i * bxr;
  });
}

// Rot on a lane bit -- ONLY ever called with masks 8,16,32 (tid3-5).
__device__ __forceinline__ void rot_lane(v32f& ar, v32f& ai, const float* __restrict__ u,
                                         const int m, const int bit) {
  const float car = bit ? u[6] : u[0], cai = bit ? u[7] : u[1];
  const float cbr = bit ? u[4] : u[2], cbi = bit ? u[5] : u[3];
  static_for<32>([&](auto ec) {
    constexpr int e = ec.value;
    const float orr = ar[e], oii = ai[e];
    const float pr = __shfl_xor(orr, m);
    const float pi = __shfl_xor(oii, m);
    ar[e] = car * orr - cai * oii + cbr * pr - cbi * pi;
    ai[e] = car * oii + cai * orr + cbr * pi + cbi * pr;
  });
}

// CNOT, local e-bit target TB; LOCALLO = qubit index of e-bit 0; control qubit C.
template <int TB, int LOCALLO, int C>
__device__ __forceinline__ void cnot_local(v32f& ar, v32f& ai, const int ibase) {
  static_for<16>([&](auto hc) {
    constexpr int h = hc.value;
    constexpr int e0 = ((h >> TB) << (TB + 1)) | (h & ((1 << TB) - 1));
    constexpr int e1 = e0 | (1 << TB);
    if constexpr (C >= LOCALLO && C < LOCALLO + 5) {
      if constexpr ((e0 >> (C - LOCALLO)) & 1) {  // static: pure register swap
        const float tr = ar[e0], ti = ai[e0];
        ar[e0] = ar[e1]; ai[e0] = ai[e1];
        ar[e1] = tr;     ai[e1] = ti;
      }
    } else {
      const int take = (ibase >> C) & 1;
      const float axr = ar[e0], axi = ai[e0], bxr = ar[e1], bxi = ai[e1];
      ar[e0] = take ? bxr : axr; ai[e0] = take ? bxi : axi;
      ar[e1] = take ? axr : bxr; ai[e1] = take ? axi : bxi;
    }
  });
}

// CNOT, lane-bit target (mask m in {8,16,32}); control qubit C (C != target).
template <int LOCALLO, int C>
__device__ __forceinline__ void cnot_lane(v32f& ar, v32f& ai, const int m, const int ibase) {
  if constexpr (C >= LOCALLO && C < LOCALLO + 5) {
    static_for<32>([&](auto ec) {
      constexpr int e = ec.value;
      if constexpr ((e >> (C - LOCALLO)) & 1) {
        ar[e] = __shfl_xor(ar[e], m);
        ai[e] = __shfl_xor(ai[e], m);
      }
    });
  } else {
    const int take = (ibase >> C) & 1;
    static_for<32>([&](auto ec) {
      constexpr int e = ec.value;
      const float pr = __shfl_xor(ar[e], m);
      const float pi = __shfl_xor(ai[e], m);
      ar[e] = take ? pr : ar[e];
      ai[e] = take ? pi : ai[e];
    });
  }
}

// ---------------- prep: 96 Rot matrices ----------------
__global__ void qsim_prep(const float* __restrict__ w, float* __restrict__ gm) {
  const int i = threadIdx.x;
  if (i < 96) {
    const float phi = w[i * 3 + 0];
    const float th  = w[i * 3 + 1];
    const float om  = w[i * 3 + 2];
    float st, ct; sincosf(0.5f * th, &st, &ct);
    float sa, ca; sincosf(0.5f * (phi + om), &sa, &ca);
    float sb, cb; sincosf(0.5f * (phi - om), &sb, &cb);
    float* u = gm + i * 8;
    u[0] =  ct * ca; u[1] = -ct * sa;   // m00
    u[2] = -st * cb; u[3] = -st * sb;   // m01
    u[4] =  st * cb; u[5] = -st * sb;   // m10
    u[6] =  ct * ca; u[7] =  ct * sa;   // m11
  }
}

// ---------------- Sweep P : rots 0-7, prefix (32 amps) ----------------
template <int L>
__global__ void __launch_bounds__(NTH) sweepP(float2* __restrict__ st,
                                              const float* __restrict__ x,
                                              const float* __restrict__ gm) {
  const int tid = threadIdx.x;
  const int s  = blockIdx.x >> 2;
  const int fb = blockIdx.x & 3;
  // amp: a0-4=e | a5-7=tid3-5 | a8-10=tid6-8 | a11-12=fb | a13-15=tid0-2
  const int ibase = (((tid >> 3) & 7) << 5) | (((tid >> 6) & 7) << 8) |
                    (fb << 11) | ((tid & 7) << 13);
  // linear: a5-7->p0-2 | a13-15->p3-5 | a0-4->p6-10 (loop) | a8-10->p11-13 | a11-12->p14-15
  const int pbase = ((tid >> 3) & 7) | ((tid & 7) << 3) |
                    (((tid >> 6) & 7) << 11) | (fb << 14);
  const int SK = (pbase >> 11) & 31;   // skew: loop index e -> e ^ SK (bits 6-10)
  float2* __restrict__ base = st + (s << 16) + pbase;
  constexpr int r = L + 1;
  const float* __restrict__ gl = gm + L * 128;
  v32f ar, ai;

  if constexpr (L == 0) {
    // init: |psi> = prod_q v_q, v_q = Rot_0(q)*RX(x_q)|0>  (ALL 16 rots folded)
    __shared__ float iv[16][4];
    if (tid < 16) {
      const float* u = gm + tid * 8;
      float sx, cx; sincosf(0.5f * x[s * 16 + tid], &sx, &cx);
      iv[tid][0] = u[0] * cx + u[3] * sx;
      iv[tid][1] = u[1] * cx - u[2] * sx;
      iv[tid][2] = u[4] * cx + u[7] * sx;
      iv[tid][3] = u[5] * cx - u[6] * sx;
    }
    __syncthreads();
    float Tr = 1.f, Ti = 0.f;
    #pragma unroll
    for (int b = 5; b <= 15; ++b) {
      const int bit = (ibase >> b) & 1;
      const float fr = iv[b][2 * bit], fi = iv[b][2 * bit + 1];
      const float nr = Tr * fr - Ti * fi; Ti = Tr * fi + Ti * fr; Tr = nr;
    }
    ar[0] = Tr; ai[0] = Ti;
    static_for<5>([&](auto bc) {
      constexpr int bI = bc.value;
      const float v0r = iv[bI][0], v0i = iv[bI][1], v1r = iv[bI][2], v1i = iv[bI][3];
      static_for<(1 << bI)>([&](auto kc) {
        constexpr int k = kc.value;
        constexpr int k1 = k | (1 << bI);
        const float kr = ar[k], ki = ai[k];
        ar[k1] = kr * v1r - ki * v1i; ai[k1] = kr * v1i + ki * v1r;
        ar[k]  = kr * v0r - ki * v0i; ai[k]  = kr * v0i + ki * v0r;
      });
    });
  } else {
    #pragma unroll
    for (int e = 0; e < 32; ++e) {        // contiguous 16KB block, skew-permuted
      const float2 v = base[(e ^ SK) << 6];
      ar[e] = v.x; ai[e] = v.y;
    }
    // deferred wraps of layer L-1: t=k (local), c=16-L+k in a11-15 (ibase)
    static_for<L>([&](auto kc) {
      constexpr int k = kc.value;
      constexpr int C = 16 - L + k;
      cnot_local<k, 0, C>(ar, ai, ibase);
    });
    rot_local<0>(ar, ai, gl);
    rot_local<1>(ar, ai, gl + 8);
    rot_local<2>(ar, ai, gl + 16);
    rot_local<3>(ar, ai, gl + 24);
    rot_local<4>(ar, ai, gl + 32);
    rot_lane(ar, ai, gl + 40, 8,  (tid >> 3) & 1);   // R_L(5)
    rot_lane(ar, ai, gl + 48, 16, (tid >> 4) & 1);   // R_L(6)
    rot_lane(ar, ai, gl + 56, 32, (tid >> 5) & 1);   // R_L(7)
  }

  // ring prefix: g = 0..7-r, t = g+r in [r,7]
  static_for<8 - r>([&](auto gc) {
    constexpr int g = gc.value;
    constexpr int t = g + r;
    if constexpr (t <= 4) cnot_local<t, 0, g>(ar, ai, ibase);
    else                  cnot_lane<0, g>(ar, ai, 1 << (t - 2), ibase);  // 5,6,7 -> 8,16,32
  });

  #pragma unroll
  for (int e = 0; e < 32; ++e) {
    float2 v; v.x = ar[e]; v.y = ai[e];
    base[(e ^ SK) << 6] = v;
  }
}

// ---------------- Sweep Q : rots 8-15, ring mid (32 amps) ----------------
template <int L>
__global__ void __launch_bounds__(NTH) sweepQ(float2* __restrict__ st,
                                              const float* __restrict__ gm) {
  const int tid = threadIdx.x;
  const int s  = blockIdx.x >> 2;
  const int fb = blockIdx.x & 3;
  // amp: a8-12=e | a5-7=tid0-2 | a13-15=tid3-5 | a0-2=tid6-8 | a3-4=fb
  const int ibase = ((tid >> 6) & 7) | (fb << 3) | ((tid & 7) << 5) |
                    (((tid >> 3) & 7) << 13);
  // linear: a5-7->p0-2 | a13-15->p3-5 | a0-2->p6-8 | a3-4->p9-10 | a8-12->p11-15 (loop)
  const int pbase = (tid & 7) | (((tid >> 3) & 7) << 3) |
                    (((tid >> 6) & 7) << 6) | (fb << 9);
  const int pb_lo  = pbase & 63;       // lanes, bits 0-5
  const int pb_mid = pbase & 0x7C0;    // wave/fb, bits 6-10 (gets skew-XORed by e)
  float2* __restrict__ base = st + (s << 16) + pb_lo;
  constexpr int r = L + 1;
  const float* __restrict__ gl = gm + L * 128;
  v32f ar, ai;
  #pragma unroll
  for (int e = 0; e < 32; ++e) {       // skew spreads bits 6-10 across the loop
    const float2 v = base[(e << 11) | (pb_mid ^ (e << 6))];
    ar[e] = v.x; ai[e] = v.y;
  }
  if constexpr (L > 0) {  // layer 0's rots were folded into init
    rot_local<0>(ar, ai, gl + 64);                   // R_L(8)
    rot_local<1>(ar, ai, gl + 72);                   // R_L(9)
    rot_local<2>(ar, ai, gl + 80);                   // R_L(10)
    rot_local<3>(ar, ai, gl + 88);                   // R_L(11)
    rot_local<4>(ar, ai, gl + 96);                   // R_L(12)
    rot_lane(ar, ai, gl + 104, 8,  (tid >> 3) & 1);  // R_L(13)
    rot_lane(ar, ai, gl + 112, 16, (tid >> 4) & 1);  // R_L(14)
    rot_lane(ar, ai, gl + 120, 32, (tid >> 5) & 1);  // R_L(15)
  }
  // ring mid: g = 8-r..15-r, t = g+r in [8,15]
  static_for<8>([&](auto gc) {
    constexpr int g = 8 - r + gc.value;
    constexpr int t = g + r;
    if constexpr (t <= 12) cnot_local<t - 8, 8, g>(ar, ai, ibase);
    else                   cnot_lane<8, g>(ar, ai, 1 << (t - 10), ibase);  // 13,14,15 -> 8,16,32
  });

  #pragma unroll
  for (int e = 0; e < 32; ++e) {
    float2 v; v.x = ar[e]; v.y = ai[e];
    base[(e << 11) | (pb_mid ^ (e << 6))] = v;
  }
}

// ---------------- final: wraps_5 + measurement (read-only, P-tiling) ----------------
__global__ void __launch_bounds__(NTH) finalK(const float2* __restrict__ st,
                                              float* __restrict__ part) {
  const int tid = threadIdx.x;
  const int s  = blockIdx.x >> 2;
  const int fb = blockIdx.x & 3;
  const int ibase = (((tid >> 3) & 7) << 5) | (((tid >> 6) & 7) << 8) |
                    (fb << 11) | ((tid & 7) << 13);
  const int pbase = ((tid >> 3) & 7) | ((tid & 7) << 3) |
                    (((tid >> 6) & 7) << 11) | (fb << 14);
  const int SK = (pbase >> 11) & 31;
  const float2* __restrict__ base = st + (s << 16) + pbase;
  v32f ar, ai;
  #pragma unroll
  for (int e = 0; e < 32; ++e) {
    const float2 v = base[(e ^ SK) << 6];
    ar[e] = v.x; ai[e] = v.y;
  }
  // wraps_5 (r=6): t=k (k=0..5), c=10+k (a10 wave, a11-12 fb, a13-15 tid0-2)
  static_for<6>([&](auto kc) {
    constexpr int k = kc.value;
    constexpr int C = 10 + k;
    if constexpr (k <= 4) cnot_local<k, 0, C>(ar, ai, ibase);
    else                  cnot_lane<0, C>(ar, ai, 8, ibase);   // t=5 -> tid3 mask 8
  });
  __shared__ float red[8][16];
  float tot = 0.f, sl0 = 0.f, sl1 = 0.f, sl2 = 0.f, sl3 = 0.f, sl4 = 0.f;
  static_for<32>([&](auto ec) {
    constexpr int e = ec.value;
    const float p = ar[e] * ar[e] + ai[e] * ai[e];
    tot += p;
    if constexpr (e & 1)  sl0 -= p; else sl0 += p;
    if constexpr (e & 2)  sl1 -= p; else sl1 += p;
    if constexpr (e & 4)  sl2 -= p; else sl2 += p;
    if constexpr (e & 8)  sl3 -= p; else sl3 += p;
    if constexpr (e & 16) sl4 -= p; else sl4 += p;
  });
  const float sl[5] = {sl0, sl1, sl2, sl3, sl4};
  const int wv = tid >> 6;
  static_for<16>([&](auto qc) {
    constexpr int q = qc.value;
    float v;
    if constexpr (q < 5) v = sl[q];
    else v = ((ibase >> q) & 1) ? -tot : tot;
    v += __shfl_xor(v, 1);  v += __shfl_xor(v, 2);  v += __shfl_xor(v, 4);
    v += __shfl_xor(v, 8);  v += __shfl_xor(v, 16); v += __shfl_xor(v, 32);
    if ((tid & 63) == 0) red[wv][q] = v;
  });
  __syncthreads();
  if (tid < 16) {
    float a = 0.f;
    #pragma unroll
    for (int w8 = 0; w8 < 8; ++w8) a += red[w8][tid];
    part[blockIdx.x * 16 + tid] = a;
  }
}

// ---------------- final reduce: 4 block-partials -> out ----------------
__global__ void __launch_bounds__(NTH) reduceK(const float* __restrict__ part,
                                               float* __restrict__ out) {
  const int j = blockIdx.x * NTH + threadIdx.x;  // j = s*16 + q, j < 8192
  const int s = j >> 4, q = j & 15;
  float a = 0.f;
  #pragma unroll
  for (int f = 0; f < 4; ++f) a += part[(s << 6) + f * 16 + q];
  out[j] = a;
}

extern "C" void kernel_launch(void* const* d_in, const int* in_sizes, int n_in,
                              void* d_out, int out_size, void* d_ws, size_t ws_size,
                              hipStream_t stream) {
  (void)in_sizes; (void)n_in; (void)out_size;
  const float* x = (const float*)d_in[0];
  const float* w = (const float*)d_in[1];
  float* out = (float*)d_out;
  float* gm   = (float*)d_ws;                          // 768 floats
  float* part = (float*)((char*)d_ws + 4096);          // 512*4*16 floats = 128 KB
  float2* st  = (float2*)((char*)d_ws + 524288);       // state, chunked to fit ws

  const size_t avail = ws_size > 524288 ? ws_size - 524288 : 0;
  long long chunk = (long long)(avail / 524288);       // 512 KB per sample
  if (chunk > 256) chunk = 256;                        // 128 MB chunk
  if (chunk < 1) chunk = 1;

  qsim_prep<<<dim3(1), dim3(128), 0, stream>>>(w, gm);
  for (int s0 = 0; s0 < 512; s0 += (int)chunk) {
    const int ns = (512 - s0) < (int)chunk ? (512 - s0) : (int)chunk;
    const dim3 g(ns * 4), b(NTH);
    const float* xs = x + s0 * 16;
    float* pp = part + (size_t)s0 * 64;
    sweepP<0><<<g, b, 0, stream>>>(st, xs, gm);
    sweepQ<0><<<g, b, 0, stream>>>(st, gm);
    sweepP<1><<<g, b, 0, stream>>>(st, xs, gm);
    sweepQ<1><<<g, b, 0, stream>>>(st, gm);
    sweepP<2><<<g, b, 0, stream>>>(st, xs, gm);
    sweepQ<2><<<g, b, 0, stream>>>(st, gm);
    sweepP<3><<<g, b, 0, stream>>>(st, xs, gm);
    sweepQ<3><<<g, b, 0, stream>>>(st, gm);
    sweepP<4><<<g, b, 0, stream>>>(st, xs, gm);
    sweepQ<4><<<g, b, 0, stream>>>(st, gm);
    sweepP<5><<<g, b, 0, stream>>>(st, xs, gm);
    sweepQ<5><<<g, b, 0, stream>>>(st, gm);
    finalK<<<g, b, 0, stream>>>(st, pp);
  }
  reduceK<<<dim3(16), dim3(NTH), 0, stream>>>(part, out);
}